// Round 2
// baseline (97.435 us; speedup 1.0000x reference)
//
#include <hip/hip_runtime.h>

// Reference: out[b,h,w,i] = in[b, h + i/8, w + i%8, 0]
//   in : (8, 512, 512, 1) f32
//   out: (8, 505, 505, 64) f32   (522 MB -> write-BW bound)
//
// Each thread writes one float4 of the output (4 consecutive i values).
// For i = 4*i4 .. 4*i4+3: row offset r = i4>>1, col base c = (i4&1)*4,
// so the 4 source elements are 4 consecutive floats of one input row.

#define BATCH   8
#define W_IN    512
#define HW_OUT  505

typedef float f32x4 __attribute__((ext_vector_type(4)));

__global__ __launch_bounds__(256) void unfold_kernel(
    const float* __restrict__ in, float* __restrict__ out, int total4)
{
    int idx    = blockIdx.x * blockDim.x + threadIdx.x;
    int stride = gridDim.x * blockDim.x;
    f32x4* __restrict__ out4 = reinterpret_cast<f32x4*>(out);

    for (int t = idx; t < total4; t += stride) {
        int i4  = t & 15;        // 16 float4 per output pixel (64 floats)
        int pos = t >> 4;        // flat (b, h, w)
        int w   = pos % HW_OUT;
        int tmp = pos / HW_OUT;
        int h   = tmp % HW_OUT;
        int b   = tmp / HW_OUT;

        int r = i4 >> 1;         // (4*i4)/8  : window row 0..7
        int c = (i4 & 1) * 4;    // (4*i4)%8  : window col base {0,4}

        const float* __restrict__ src =
            in + ((b * W_IN + h + r) * W_IN + (w + c));

        f32x4 v;
        v.x = src[0];
        v.y = src[1];
        v.z = src[2];
        v.w = src[3];
        __builtin_nontemporal_store(v, out4 + t);
    }
}

extern "C" void kernel_launch(void* const* d_in, const int* in_sizes, int n_in,
                              void* d_out, int out_size, void* d_ws, size_t ws_size,
                              hipStream_t stream)
{
    const float* in  = (const float*)d_in[0];   // (8,512,512,1) f32
    float*       out = (float*)d_out;           // (8,505,505,64) f32

    const int total4 = BATCH * HW_OUT * HW_OUT * 16;  // 32,643,200 float4
    const int block  = 256;
    int grid = (total4 + block - 1) / block;
    const int max_grid = 256 * 8;                     // ~2048 blocks, grid-stride
    if (grid > max_grid) grid = max_grid;

    unfold_kernel<<<grid, block, 0, stream>>>(in, out, total4);
}